// Round 7
// baseline (190.254 us; speedup 1.0000x reference)
//
#include <hip/hip_runtime.h>
#include <stdint.h>

typedef unsigned short u16t;
typedef __attribute__((ext_vector_type(8))) short bf16x8;
typedef __attribute__((ext_vector_type(4))) float f32x4;
typedef __attribute__((ext_vector_type(16))) float f32x16;

__device__ __forceinline__ float2 up2(uint32_t u) {
    return make_float2(__uint_as_float(u << 16), __uint_as_float(u & 0xFFFF0000u));
}
__device__ __forceinline__ uint32_t pk_bf16(float a, float b) {
    uint32_t r;
    asm("v_cvt_pk_bf16_f32 %0, %1, %2" : "=v"(r) : "v"(a), "v"(b));
    return r;   // lo16 = bf16(a) RNE, hi16 = bf16(b)
}

// ---------------------------------------------------------------------------
// Pre-kernel (35 blocks):
//  blocks 0-31 : W1d (1024x64 fp32) -> Wt bf16 [g][k][o][j]   (131072 B)
//  blocks 32-34: W2d (16x384 fp32)  -> W2b bf16 [16][384] row-major (12288 B)
// ---------------------------------------------------------------------------
__global__ void __launch_bounds__(256) prep_weights(const float* __restrict__ W1d,
                                                    const float* __restrict__ W2d,
                                                    u16t* __restrict__ Wt,
                                                    uint4* __restrict__ W2b) {
    int bid = blockIdx.x;
    if (bid < 32) {
        int t = bid * 256 + threadIdx.x;          // 0..8191
        int g = t >> 10, k = (t >> 7) & 7, o = t & 127;
        const float* src = W1d + (((g << 7) + o) << 6) + (k << 3);
        u16t* dst = Wt + ((((g << 3) + k) << 7) + o) * 8;
#pragma unroll
        for (int j = 0; j < 8; ++j) {
            uint32_t u = __float_as_uint(src[j]);
            uint32_t r = (u + 0x7FFFu + ((u >> 16) & 1u)) >> 16;   // RN to bf16
            dst[j] = (u16t)r;
        }
    } else {
        int idx = (bid - 32) * 256 + threadIdx.x;  // 0..767 (chunks of 8 f32)
        const float4* s = (const float4*)W2d + idx * 2;
        float4 A = s[0], B = s[1];
        uint4 p;
        p.x = pk_bf16(A.x, A.y); p.y = pk_bf16(A.z, A.w);
        p.z = pk_bf16(B.x, B.y); p.w = pk_bf16(B.z, B.w);
        W2b[idx] = p;
    }
}

#define LGKM_FENCE() do {                                          \
    asm volatile("s_waitcnt lgkmcnt(0)" ::: "memory");             \
    __builtin_amdgcn_sched_barrier(0);                             \
} while (0)

#define SOFT_BARRIER() do {                                        \
    asm volatile("s_waitcnt lgkmcnt(0)" ::: "memory");             \
    __builtin_amdgcn_s_barrier();                                  \
    asm volatile("" ::: "memory");                                 \
    __builtin_amdgcn_sched_barrier(0);                             \
} while (0)

// ---------------------------------------------------------------------------
// Fused kernel: one block (256 thr) per (b,h).  NO x staging in LDS — x tile
// is L2/L3-hot (FETCH < |x| across R4-R6); MFMA operands load straight from
// global f32 and convert in-register.  LDS = ys 2048 + zs 2560 = 4608 B
// -> 6 blocks/CU (24 waves).  One s_barrier total.
//  phase 2: y = W2d.x^T via mfma_16x16x32_bf16 (per-wave dup, e-slice write)
//  phase 3: conv1d + softmax (VALU) -> attn bf16 zs16[32][40]; issue xcv
//  phase 4: out = attn.x via mfma_32x32x16_bf16 (B from xcv registers)
// ---------------------------------------------------------------------------
template <bool WBF>
__global__ void __launch_bounds__(256, 6) dynamixer_fused(
    const float* __restrict__ x,
    const float* __restrict__ W2d,
    const float* __restrict__ b2d,
    const float* __restrict__ W1d,
    const float* __restrict__ b1d,
    const u16t* __restrict__ Wt,
    const u16t* __restrict__ W2b,
    float* __restrict__ out)
{
    __shared__ alignas(16) float ys[512];       // y, flat e*32+w
    __shared__ alignas(16) u16t zs16[32 * 40];  // attn bf16, row stride 40

    const int t = threadIdx.x;
    const int blk = blockIdx.x;                           // b*32 + h
    const float* __restrict__ xsrc = x + (size_t)blk * 12288;
    const int wid = t >> 6, lane = t & 63;
    const int g2 = lane >> 5, l31 = lane & 31;
    const int g = t >> 5, l = t & 31;

    // ---------------- phase 2: conv2d via MFMA 16x16x32 ----------------
    {
        const int g4 = lane >> 4, m = lane & 15;          // A row=e, B col=w=m
        f32x4 c0, c1;
#pragma unroll
        for (int r = 0; r < 4; ++r) { c0[r] = 0.f; c1[r] = 0.f; }
        const float* __restrict__ xr0 = xsrc + m * 384;
        const float* __restrict__ xr1 = xsrc + (m + 16) * 384;
#pragma unroll 6
        for (int ks = 0; ks < 12; ++ks) {
            const int d0 = ks * 32 + g4 * 8;
            float4 xa = *(const float4*)(xr0 + d0);
            float4 xb = *(const float4*)(xr0 + d0 + 4);
            float4 xc = *(const float4*)(xr1 + d0);
            float4 xd = *(const float4*)(xr1 + d0 + 4);
            union { uint4 u; bf16x8 v; } b0, b1;
            b0.u.x = pk_bf16(xa.x, xa.y); b0.u.y = pk_bf16(xa.z, xa.w);
            b0.u.z = pk_bf16(xb.x, xb.y); b0.u.w = pk_bf16(xb.z, xb.w);
            b1.u.x = pk_bf16(xc.x, xc.y); b1.u.y = pk_bf16(xc.z, xc.w);
            b1.u.z = pk_bf16(xd.x, xd.y); b1.u.w = pk_bf16(xd.z, xd.w);
            bf16x8 a;
            if (WBF) {
                a = *(const bf16x8*)&W2b[m * 384 + d0];
            } else {
                const float* wf = W2d + m * 384 + d0;
                float4 wa = *(const float4*)wf, wb = *(const float4*)(wf + 4);
                union { uint4 u; bf16x8 v; } cvt;
                cvt.u.x = pk_bf16(wa.x, wa.y); cvt.u.y = pk_bf16(wa.z, wa.w);
                cvt.u.z = pk_bf16(wb.x, wb.y); cvt.u.w = pk_bf16(wb.z, wb.w);
                a = cvt.v;
            }
            c0 = __builtin_amdgcn_mfma_f32_16x16x32_bf16(a, b0.v, c0, 0, 0, 0);
            c1 = __builtin_amdgcn_mfma_f32_16x16x32_bf16(a, b1.v, c1, 0, 0, 0);
        }
        // write only this wave's e-slice [4*wid, 4*wid+4): C row=g4*4+r, col=m
        if (g4 == wid) {
            float4 bb = *(const float4*)&b2d[wid * 4];
            float bbv[4] = {bb.x, bb.y, bb.z, bb.w};
#pragma unroll
            for (int r = 0; r < 4; ++r) {
                ys[(4 * wid + r) * 32 + m]      = c0[r] + bbv[r];
                ys[(4 * wid + r) * 32 + 16 + m] = c1[r] + bbv[r];
            }
        }
    }
    LGKM_FENCE();     // ys slice visible intra-wave (g = 2wid, 2wid+1)

    // ---------------- phase 3: conv1d + softmax -> attn bf16 ----------
    {
        float2 ac2[4];
#pragma unroll
        for (int j = 0; j < 4; ++j) ac2[j] = make_float2(0.f, 0.f);
        if (WBF) {
            const uint4* __restrict__ wpt = (const uint4*)Wt + (g << 10);
#pragma unroll
            for (int k = 0; k < 8; ++k) {
                const float2* yp = (const float2*)&ys[(g << 6) + (k << 3)];
                float2 y0 = yp[0], y1 = yp[1], y2 = yp[2], y3 = yp[3];
#pragma unroll
                for (int j = 0; j < 4; ++j) {
                    uint4 wq = wpt[(k << 7) + l + (j << 5)];
                    ac2[j] += up2(wq.x) * y0;
                    ac2[j] += up2(wq.y) * y1;
                    ac2[j] += up2(wq.z) * y2;
                    ac2[j] += up2(wq.w) * y3;
                }
            }
        } else {
#pragma unroll
            for (int k = 0; k < 8; ++k) {
                const float2* yp = (const float2*)&ys[(g << 6) + (k << 3)];
                float2 y0 = yp[0], y1 = yp[1], y2 = yp[2], y3 = yp[3];
#pragma unroll
                for (int j = 0; j < 4; ++j) {
                    const float2* wr = (const float2*)(W1d + (((g << 7) + l + (j << 5)) << 6) + (k << 3));
                    ac2[j] += wr[0] * y0;
                    ac2[j] += wr[1] * y1;
                    ac2[j] += wr[2] * y2;
                    ac2[j] += wr[3] * y3;
                }
            }
        }
        float acc[4];
#pragma unroll
        for (int j = 0; j < 4; ++j)
            acc[j] = ac2[j].x + ac2[j].y + b1d[(g << 7) + (j << 5) + l];

        // softmax over v (= lane within 32-lane group), row u = 4g+j
#pragma unroll
        for (int j = 0; j < 4; ++j) {
            float mx = acc[j];
#pragma unroll
            for (int s = 16; s >= 1; s >>= 1) mx = fmaxf(mx, __shfl_xor(mx, s, 32));
            float p = __expf(acc[j] - mx);
            float ssum = p;
#pragma unroll
            for (int s = 16; s >= 1; s >>= 1) ssum += __shfl_xor(ssum, s, 32);
            float pv = __fdividef(p, ssum);
            zs16[((g << 2) + j) * 40 + l] = (u16t)pk_bf16(pv, pv);
        }
    }

    // ---------------- issue phase-4 x column loads (fly across barrier) ----
    float xcv[48];   // x[v = h8*16+g2*8+j][d = wid*96+i*32+l31]
    {
        const float* __restrict__ base = xsrc + wid * 96 + l31;
#pragma unroll
        for (int h8 = 0; h8 < 2; ++h8)
#pragma unroll
            for (int j = 0; j < 8; ++j)
#pragma unroll
                for (int i = 0; i < 3; ++i)
                    xcv[(h8 * 8 + j) * 3 + i] = base[(h8 * 16 + g2 * 8 + j) * 384 + i * 32];
    }

    SOFT_BARRIER();   // zs visible across waves; raw barrier keeps xcv in flight

    // ---------------- phase 4: out = attn . x via MFMA 32x32x16 ----------
    {
        bf16x8 Bf[6];                                      // [h8][i]
#pragma unroll
        for (int h8 = 0; h8 < 2; ++h8)
#pragma unroll
            for (int i = 0; i < 3; ++i) {
                union { uint4 u; bf16x8 v; } cv;
                cv.u.x = pk_bf16(xcv[h8 * 24 + 0 + i],  xcv[h8 * 24 + 3 + i]);
                cv.u.y = pk_bf16(xcv[h8 * 24 + 6 + i],  xcv[h8 * 24 + 9 + i]);
                cv.u.z = pk_bf16(xcv[h8 * 24 + 12 + i], xcv[h8 * 24 + 15 + i]);
                cv.u.w = pk_bf16(xcv[h8 * 24 + 18 + i], xcv[h8 * 24 + 21 + i]);
                Bf[h8 * 3 + i] = cv.v;
            }
        // A frags: attn[u = l31][k = g2*8 + j (+16)]
        bf16x8 A0 = *(const bf16x8*)&zs16[l31 * 40 + g2 * 8];
        bf16x8 A1 = *(const bf16x8*)&zs16[l31 * 40 + 16 + g2 * 8];
        float* __restrict__ obase = out + (size_t)blk * 12288;
#pragma unroll
        for (int i = 0; i < 3; ++i) {
            f32x16 acc16;
#pragma unroll
            for (int r = 0; r < 16; ++r) acc16[r] = 0.f;
            acc16 = __builtin_amdgcn_mfma_f32_32x32x16_bf16(A0, Bf[i],     acc16, 0, 0, 0);
            acc16 = __builtin_amdgcn_mfma_f32_32x32x16_bf16(A1, Bf[3 + i], acc16, 0, 0, 0);
            const int d = wid * 96 + i * 32 + l31;
#pragma unroll
            for (int r = 0; r < 16; ++r) {
                const int u = (r & 3) + 8 * (r >> 2) + 4 * g2;
                obase[u * 384 + d] = acc16[r];
            }
        }
    }
}

// ---------------------------------------------------------------------------
extern "C" void kernel_launch(void* const* d_in, const int* in_sizes, int n_in,
                              void* d_out, int out_size, void* d_ws, size_t ws_size,
                              hipStream_t stream) {
    const float* x   = (const float*)d_in[0];
    const float* W2d = (const float*)d_in[1];
    const float* b2d = (const float*)d_in[2];
    const float* W1d = (const float*)d_in[3];
    const float* b1d = (const float*)d_in[4];
    float* out = (float*)d_out;

    const size_t wt_bytes  = 8 * 8 * 128 * 8 * sizeof(u16t);   // 131072
    const size_t w2b_bytes = 16 * 384 * sizeof(u16t);          // 12288
    if (ws_size >= wt_bytes + w2b_bytes) {
        u16t* Wt = (u16t*)d_ws;
        u16t* W2b = (u16t*)((char*)d_ws + wt_bytes);
        prep_weights<<<35, 256, 0, stream>>>(W1d, W2d, Wt, (uint4*)W2b);
        dynamixer_fused<true><<<4096, 256, 0, stream>>>(x, W2d, b2d, W1d, b1d, Wt, W2b, out);
    } else {
        dynamixer_fused<false><<<4096, 256, 0, stream>>>(x, W2d, b2d, W1d, b1d, nullptr, nullptr, out);
    }
}

// Round 8
// 152.636 us; speedup vs baseline: 1.2465x; 1.2465x over previous
//
#include <hip/hip_runtime.h>
#include <stdint.h>

typedef unsigned short u16t;
typedef __attribute__((ext_vector_type(8))) short bf16x8;
typedef __attribute__((ext_vector_type(4))) float f32x4;
typedef __attribute__((ext_vector_type(16))) float f32x16;

__device__ __forceinline__ float2 up2(uint32_t u) {
    return make_float2(__uint_as_float(u << 16), __uint_as_float(u & 0xFFFF0000u));
}
__device__ __forceinline__ uint32_t pk_bf16(float a, float b) {
    uint32_t r;
    asm("v_cvt_pk_bf16_f32 %0, %1, %2" : "=v"(r) : "v"(a), "v"(b));
    return r;   // lo16 = bf16(a) RNE, hi16 = bf16(b)
}

// ---------------------------------------------------------------------------
// Pre-kernel (35 blocks):
//  blocks 0-31 : W1d (1024x64 fp32) -> Wt bf16 [g][k][o][j]   (131072 B)
//  blocks 32-34: W2d (16x384 fp32)  -> W2b bf16 [16][384] row-major (12288 B)
// ---------------------------------------------------------------------------
__global__ void __launch_bounds__(256) prep_weights(const float* __restrict__ W1d,
                                                    const float* __restrict__ W2d,
                                                    u16t* __restrict__ Wt,
                                                    uint4* __restrict__ W2b) {
    int bid = blockIdx.x;
    if (bid < 32) {
        int t = bid * 256 + threadIdx.x;          // 0..8191
        int g = t >> 10, k = (t >> 7) & 7, o = t & 127;
        const float* src = W1d + (((g << 7) + o) << 6) + (k << 3);
        u16t* dst = Wt + ((((g << 3) + k) << 7) + o) * 8;
#pragma unroll
        for (int j = 0; j < 8; ++j) {
            uint32_t u = __float_as_uint(src[j]);
            uint32_t r = (u + 0x7FFFu + ((u >> 16) & 1u)) >> 16;   // RN to bf16
            dst[j] = (u16t)r;
        }
    } else {
        int idx = (bid - 32) * 256 + threadIdx.x;  // 0..767 (chunks of 8 f32)
        const float4* s = (const float4*)W2d + idx * 2;
        float4 A = s[0], B = s[1];
        uint4 p;
        p.x = pk_bf16(A.x, A.y); p.y = pk_bf16(A.z, A.w);
        p.z = pk_bf16(B.x, B.y); p.w = pk_bf16(B.z, B.w);
        W2b[idx] = p;
    }
}

// ---------------------------------------------------------------------------
// Fused kernel: ONE WAVE per (b,h) tile; 256-thread blocks hold 4 independent
// waves; grid 1024.  NO barriers, NO fences — all producer/consumer pairs are
// same-wave, ordered by the compiler's own lgkmcnt insertion.  Latency hiding
// comes from ~24-32 independent waves per CU (TLP, not per-wave ILP).
//  phase 2: y[16][32] = W2d.x^T  via mfma_16x16x32_bf16 (full tile per wave)
//  phase 3: conv1d + softmax (VALU; lane = (gh,l), 4 groups per lane)
//  phase 4: out = attn.x via 2x mfma_32x32x16_bf16 per 32-col block (12 blocks)
// LDS per block: 4*(2048 + 2560) = 18432 B.  x never staged (L2/L3-resident).
// ---------------------------------------------------------------------------
template <bool WBF>
__global__ void __launch_bounds__(256, 5) dynamixer_fused(
    const float* __restrict__ x,
    const float* __restrict__ W2d,
    const float* __restrict__ b2d,
    const float* __restrict__ W1d,
    const float* __restrict__ b1d,
    const u16t* __restrict__ Wt,
    const u16t* __restrict__ W2b,
    float* __restrict__ out)
{
    __shared__ alignas(16) float ys[4][512];        // y, flat e*32+w, per wave
    __shared__ alignas(16) u16t zs16[4][32 * 40];   // attn bf16, stride 40

    const int t = threadIdx.x;
    const int wid = t >> 6, lane = t & 63;
    const int T = blockIdx.x * 4 + wid;                  // (b,h) tile id
    const float* __restrict__ xsrc = x + (size_t)T * 12288;
    float* const ysW = ys[wid];
    u16t* const zsW = zs16[wid];

    const int gh = lane >> 5, l31 = lane & 31;

    // ---------------- phase 2: conv2d via MFMA 16x16x32 ----------------
    {
        const int g4 = lane >> 4, m = lane & 15;          // A row=e, B col=w=m
        f32x4 c0, c1;
#pragma unroll
        for (int r = 0; r < 4; ++r) { c0[r] = 0.f; c1[r] = 0.f; }
        const float* __restrict__ xr0 = xsrc + m * 384;
        const float* __restrict__ xr1 = xsrc + (m + 16) * 384;
#pragma unroll 4
        for (int ks = 0; ks < 12; ++ks) {
            const int d0 = ks * 32 + g4 * 8;
            float4 xa = *(const float4*)(xr0 + d0);
            float4 xb = *(const float4*)(xr0 + d0 + 4);
            float4 xc = *(const float4*)(xr1 + d0);
            float4 xd = *(const float4*)(xr1 + d0 + 4);
            union { uint4 u; bf16x8 v; } b0, b1;
            b0.u.x = pk_bf16(xa.x, xa.y); b0.u.y = pk_bf16(xa.z, xa.w);
            b0.u.z = pk_bf16(xb.x, xb.y); b0.u.w = pk_bf16(xb.z, xb.w);
            b1.u.x = pk_bf16(xc.x, xc.y); b1.u.y = pk_bf16(xc.z, xc.w);
            b1.u.z = pk_bf16(xd.x, xd.y); b1.u.w = pk_bf16(xd.z, xd.w);
            bf16x8 a;
            if (WBF) {
                a = *(const bf16x8*)&W2b[m * 384 + d0];
            } else {
                const float* wf = W2d + m * 384 + d0;
                float4 wa = *(const float4*)wf, wb = *(const float4*)(wf + 4);
                union { uint4 u; bf16x8 v; } cvt;
                cvt.u.x = pk_bf16(wa.x, wa.y); cvt.u.y = pk_bf16(wa.z, wa.w);
                cvt.u.z = pk_bf16(wb.x, wb.y); cvt.u.w = pk_bf16(wb.z, wb.w);
                a = cvt.v;
            }
            c0 = __builtin_amdgcn_mfma_f32_16x16x32_bf16(a, b0.v, c0, 0, 0, 0);
            c1 = __builtin_amdgcn_mfma_f32_16x16x32_bf16(a, b1.v, c1, 0, 0, 0);
        }
        // whole wave writes ALL of ys: C row = e = g4*4+r, col = w = m / m+16
        float4 bb = *(const float4*)&b2d[g4 * 4];
        float bbv[4] = {bb.x, bb.y, bb.z, bb.w};
#pragma unroll
        for (int r = 0; r < 4; ++r) {
            ysW[(g4 * 4 + r) * 32 + m]      = c0[r] + bbv[r];
            ysW[(g4 * 4 + r) * 32 + 16 + m] = c1[r] + bbv[r];
        }
    }
    // (same-wave LDS ordering: compiler inserts lgkmcnt; no barrier needed)

    // ---------------- phase 3: conv1d + softmax -> attn bf16 ----------
    // lane = (gh, l); each lane handles g = 2q+gh for q=0..3, v-col l.
    {
        const int l = l31;
#pragma unroll
        for (int q = 0; q < 4; ++q) {
            const int g = 2 * q + gh;
            float2 ac2[4];
#pragma unroll
            for (int j = 0; j < 4; ++j) ac2[j] = make_float2(0.f, 0.f);
            if (WBF) {
                const uint4* __restrict__ wpt = (const uint4*)Wt + (g << 10);
#pragma unroll
                for (int k = 0; k < 8; ++k) {
                    const float2* yp = (const float2*)&ysW[(g << 6) + (k << 3)];
                    float2 y0 = yp[0], y1 = yp[1], y2 = yp[2], y3 = yp[3];
#pragma unroll
                    for (int j = 0; j < 4; ++j) {
                        uint4 wq = wpt[(k << 7) + l + (j << 5)];
                        ac2[j] += up2(wq.x) * y0;
                        ac2[j] += up2(wq.y) * y1;
                        ac2[j] += up2(wq.z) * y2;
                        ac2[j] += up2(wq.w) * y3;
                    }
                }
            } else {
#pragma unroll
                for (int k = 0; k < 8; ++k) {
                    const float2* yp = (const float2*)&ysW[(g << 6) + (k << 3)];
                    float2 y0 = yp[0], y1 = yp[1], y2 = yp[2], y3 = yp[3];
#pragma unroll
                    for (int j = 0; j < 4; ++j) {
                        const float2* wr = (const float2*)(W1d + (((g << 7) + l + (j << 5)) << 6) + (k << 3));
                        ac2[j] += wr[0] * y0;
                        ac2[j] += wr[1] * y1;
                        ac2[j] += wr[2] * y2;
                        ac2[j] += wr[3] * y3;
                    }
                }
            }
            float acc[4];
#pragma unroll
            for (int j = 0; j < 4; ++j)
                acc[j] = ac2[j].x + ac2[j].y + b1d[(g << 7) + (j << 5) + l];

            // softmax over v (= lane within 32-lane half), row u = 4g+j
#pragma unroll
            for (int j = 0; j < 4; ++j) {
                float mx = acc[j];
#pragma unroll
                for (int s = 16; s >= 1; s >>= 1) mx = fmaxf(mx, __shfl_xor(mx, s, 32));
                float p = __expf(acc[j] - mx);
                float ssum = p;
#pragma unroll
                for (int s = 16; s >= 1; s >>= 1) ssum += __shfl_xor(ssum, s, 32);
                float pv = __fdividef(p, ssum);
                zsW[(4 * g + j) * 40 + l] = (u16t)pk_bf16(pv, pv);
            }
        }
    }

    // ---------------- phase 4: out = attn . x via MFMA 32x32x16 ----------
    {
        // A frags: attn[u = l31][k = gh*8 + j (+16)]
        bf16x8 A0 = *(const bf16x8*)&zsW[l31 * 40 + gh * 8];
        bf16x8 A1 = *(const bf16x8*)&zsW[l31 * 40 + 16 + gh * 8];
        float* __restrict__ obase = out + (size_t)T * 12288;
        const float* __restrict__ xb0 = xsrc + (gh * 8) * 384 + l31;        // v = gh*8+j
        const float* __restrict__ xb1 = xsrc + (16 + gh * 8) * 384 + l31;   // v = 16+gh*8+j
#pragma unroll 3
        for (int i = 0; i < 12; ++i) {
            const int d = i * 32;
            float v0[8], v1[8];
#pragma unroll
            for (int j = 0; j < 8; ++j) {
                v0[j] = xb0[j * 384 + d];
                v1[j] = xb1[j * 384 + d];
            }
            union { uint4 u; bf16x8 v; } B0, B1;
            B0.u.x = pk_bf16(v0[0], v0[1]); B0.u.y = pk_bf16(v0[2], v0[3]);
            B0.u.z = pk_bf16(v0[4], v0[5]); B0.u.w = pk_bf16(v0[6], v0[7]);
            B1.u.x = pk_bf16(v1[0], v1[1]); B1.u.y = pk_bf16(v1[2], v1[3]);
            B1.u.z = pk_bf16(v1[4], v1[5]); B1.u.w = pk_bf16(v1[6], v1[7]);
            f32x16 acc16;
#pragma unroll
            for (int r = 0; r < 16; ++r) acc16[r] = 0.f;
            acc16 = __builtin_amdgcn_mfma_f32_32x32x16_bf16(A0, B0.v, acc16, 0, 0, 0);
            acc16 = __builtin_amdgcn_mfma_f32_32x32x16_bf16(A1, B1.v, acc16, 0, 0, 0);
#pragma unroll
            for (int r = 0; r < 16; ++r) {
                const int u = (r & 3) + 8 * (r >> 2) + 4 * gh;
                obase[u * 384 + d + l31] = acc16[r];
            }
        }
    }
}

// ---------------------------------------------------------------------------
extern "C" void kernel_launch(void* const* d_in, const int* in_sizes, int n_in,
                              void* d_out, int out_size, void* d_ws, size_t ws_size,
                              hipStream_t stream) {
    const float* x   = (const float*)d_in[0];
    const float* W2d = (const float*)d_in[1];
    const float* b2d = (const float*)d_in[2];
    const float* W1d = (const float*)d_in[3];
    const float* b1d = (const float*)d_in[4];
    float* out = (float*)d_out;

    const size_t wt_bytes  = 8 * 8 * 128 * 8 * sizeof(u16t);   // 131072
    const size_t w2b_bytes = 16 * 384 * sizeof(u16t);          // 12288
    if (ws_size >= wt_bytes + w2b_bytes) {
        u16t* Wt = (u16t*)d_ws;
        u16t* W2b = (u16t*)((char*)d_ws + wt_bytes);
        prep_weights<<<35, 256, 0, stream>>>(W1d, W2d, Wt, (uint4*)W2b);
        dynamixer_fused<true><<<1024, 256, 0, stream>>>(x, W2d, b2d, W1d, b1d, Wt, W2b, out);
    } else {
        dynamixer_fused<false><<<1024, 256, 0, stream>>>(x, W2d, b2d, W1d, b1d, nullptr, nullptr, out);
    }
}

// Round 9
// 112.626 us; speedup vs baseline: 1.6893x; 1.3553x over previous
//
#include <hip/hip_runtime.h>
#include <stdint.h>

typedef unsigned short u16t;
typedef __attribute__((ext_vector_type(8))) short bf16x8;
typedef __attribute__((ext_vector_type(4))) float f32x4;
typedef __attribute__((ext_vector_type(16))) float f32x16;

__device__ __forceinline__ float2 up2(uint32_t u) {
    return make_float2(__uint_as_float(u << 16), __uint_as_float(u & 0xFFFF0000u));
}
__device__ __forceinline__ uint32_t pk_bf16(float a, float b) {
    uint32_t r;
    asm("v_cvt_pk_bf16_f32 %0, %1, %2" : "=v"(r) : "v"(a), "v"(b));
    return r;   // lo16 = bf16(a) RNE, hi16 = bf16(b)
}
__device__ __forceinline__ void gload_lds16(const float* g, float* l) {
    __builtin_amdgcn_global_load_lds(
        (const __attribute__((address_space(1))) void*)g,
        (__attribute__((address_space(3))) void*)l, 16, 0, 0);
}

// ---------------------------------------------------------------------------
// Pre-kernel (35 blocks):
//  blocks 0-31 : W1d (1024x64 fp32) -> Wt bf16 [g][k][o][j]   (131072 B)
//  blocks 32-34: W2d (16x384 fp32)  -> W2b bf16 [16][384] row-major (12288 B)
// ---------------------------------------------------------------------------
__global__ void __launch_bounds__(256) prep_weights(const float* __restrict__ W1d,
                                                    const float* __restrict__ W2d,
                                                    u16t* __restrict__ Wt,
                                                    uint4* __restrict__ W2b) {
    int bid = blockIdx.x;
    if (bid < 32) {
        int t = bid * 256 + threadIdx.x;          // 0..8191
        int g = t >> 10, k = (t >> 7) & 7, o = t & 127;
        const float* src = W1d + (((g << 7) + o) << 6) + (k << 3);
        u16t* dst = Wt + ((((g << 3) + k) << 7) + o) * 8;
#pragma unroll
        for (int j = 0; j < 8; ++j) {
            uint32_t u = __float_as_uint(src[j]);
            uint32_t r = (u + 0x7FFFu + ((u >> 16) & 1u)) >> 16;   // RN to bf16
            dst[j] = (u16t)r;
        }
    } else {
        int idx = (bid - 32) * 256 + threadIdx.x;  // 0..767 (chunks of 8 f32)
        const float4* s = (const float4*)W2d + idx * 2;
        float4 A = s[0], B = s[1];
        uint4 p;
        p.x = pk_bf16(A.x, A.y); p.y = pk_bf16(A.z, A.w);
        p.z = pk_bf16(B.x, B.y); p.w = pk_bf16(B.z, B.w);
        W2b[idx] = p;
    }
}

// ---------------------------------------------------------------------------
// Fused kernel: one block (256 thr) per (b,h).
//  phase 1: stage x[b,h] (32x384 f32 = 48KB) into LDS via global_load_lds
//           (NO dest VGPRs -> all 12 loads in flight; one vmcnt(0)).
//           LDS physical layout linear; SOURCE address applies the XOR
//           swizzle  chunk16 ^= (row & 7)  so reads can de-conflict.
//  phase 2: y = W2d.x^T via mfma_16x16x32_bf16 (per-wave dup, e-slice write)
//  phase 3: conv1d + softmax (VALU) -> attn bf16 zs16[32][40]
//  phase 4: out = attn.x via mfma_32x32x16_bf16 (B gathered from LDS, same XOR)
// LDS: 49152 + 2048 + 2560 = 53760 B -> 3 blocks/CU (12 waves).
// Barriers: 2 (stage->p2, p3->p4); p2->p3 is intra-wave (lgkm fence).
// ---------------------------------------------------------------------------
template <bool WBF>
__global__ void __launch_bounds__(256, 3) dynamixer_fused(
    const float* __restrict__ x,
    const float* __restrict__ W2d,
    const float* __restrict__ b2d,
    const float* __restrict__ W1d,
    const float* __restrict__ b1d,
    const u16t* __restrict__ Wt,
    const u16t* __restrict__ W2b,
    float* __restrict__ out)
{
    __shared__ alignas(16) float xs[32 * 384];      // fp32 x tile, linear
    __shared__ alignas(16) float ys[512];           // y, flat e*32+w
    __shared__ alignas(16) u16t zs16[32 * 40];      // attn bf16, row stride 40

    const int t = threadIdx.x;
    const int blk = blockIdx.x;                           // b*32 + h
    const float* __restrict__ xsrc = x + (size_t)blk * 12288;
    const int wid = t >> 6, lane = t & 63;
    const int g2 = lane >> 5, l31 = lane & 31;
    const int g = t >> 5, l = t & 31;

    // ---------------- phase 1: stage x via global_load_lds ----------------
    {
#pragma unroll
        for (int k = 0; k < 12; ++k) {
            const int P = wid * 768 + k * 64 + lane;      // physical 16B chunk
            const int r = P / 96;                          // row 0..31
            const int cq = P - r * 96;                     // phys chunk in row
            const int cl = cq ^ (r & 7);                   // logical chunk (XOR low3)
            gload_lds16(xsrc + r * 384 + cl * 4,
                        &xs[(size_t)(wid * 768 + k * 64) * 4]);
        }
        asm volatile("s_waitcnt vmcnt(0)" ::: "memory");
        __builtin_amdgcn_s_barrier();
        asm volatile("" ::: "memory");
    }

    // ---------------- phase 2: conv2d via MFMA 16x16x32 ----------------
    {
        const int g4 = lane >> 4, m = lane & 15;          // A row=e, B col=w=m
        const int f = m & 7;                               // row swizzle key
        f32x4 c0, c1;
#pragma unroll
        for (int r = 0; r < 4; ++r) { c0[r] = 0.f; c1[r] = 0.f; }
#pragma unroll 4
        for (int ks = 0; ks < 12; ++ks) {
            const int c = ks * 8 + g4 * 2;                 // logical 16B chunk
            const int d0 = ks * 32 + g4 * 8;
            float4 xa = *(const float4*)&xs[(m * 96 + (c ^ f)) * 4];
            float4 xb = *(const float4*)&xs[(m * 96 + ((c + 1) ^ f)) * 4];
            float4 xc = *(const float4*)&xs[((m + 16) * 96 + (c ^ f)) * 4];
            float4 xd = *(const float4*)&xs[((m + 16) * 96 + ((c + 1) ^ f)) * 4];
            union { uint4 u; bf16x8 v; } b0, b1;
            b0.u.x = pk_bf16(xa.x, xa.y); b0.u.y = pk_bf16(xa.z, xa.w);
            b0.u.z = pk_bf16(xb.x, xb.y); b0.u.w = pk_bf16(xb.z, xb.w);
            b1.u.x = pk_bf16(xc.x, xc.y); b1.u.y = pk_bf16(xc.z, xc.w);
            b1.u.z = pk_bf16(xd.x, xd.y); b1.u.w = pk_bf16(xd.z, xd.w);
            bf16x8 a;
            if (WBF) {
                a = *(const bf16x8*)&W2b[m * 384 + d0];
            } else {
                const float* wf = W2d + m * 384 + d0;
                float4 wa = *(const float4*)wf, wb = *(const float4*)(wf + 4);
                union { uint4 u; bf16x8 v; } cvt;
                cvt.u.x = pk_bf16(wa.x, wa.y); cvt.u.y = pk_bf16(wa.z, wa.w);
                cvt.u.z = pk_bf16(wb.x, wb.y); cvt.u.w = pk_bf16(wb.z, wb.w);
                a = cvt.v;
            }
            c0 = __builtin_amdgcn_mfma_f32_16x16x32_bf16(a, b0.v, c0, 0, 0, 0);
            c1 = __builtin_amdgcn_mfma_f32_16x16x32_bf16(a, b1.v, c1, 0, 0, 0);
        }
        // write only this wave's e-slice [4*wid, 4*wid+4): C row=g4*4+r, col=m
        if (g4 == wid) {
            float4 bb = *(const float4*)&b2d[wid * 4];
            float bbv[4] = {bb.x, bb.y, bb.z, bb.w};
#pragma unroll
            for (int r = 0; r < 4; ++r) {
                ys[(4 * wid + r) * 32 + m]      = c0[r] + bbv[r];
                ys[(4 * wid + r) * 32 + 16 + m] = c1[r] + bbv[r];
            }
        }
    }
    asm volatile("s_waitcnt lgkmcnt(0)" ::: "memory");    // ys visible intra-wave
    __builtin_amdgcn_sched_barrier(0);

    // ---------------- phase 3: conv1d + softmax -> attn bf16 ----------
    {
        float2 ac2[4];
#pragma unroll
        for (int j = 0; j < 4; ++j) ac2[j] = make_float2(0.f, 0.f);
        if (WBF) {
            const uint4* __restrict__ wpt = (const uint4*)Wt + (g << 10);
#pragma unroll
            for (int k = 0; k < 8; ++k) {
                const float2* yp = (const float2*)&ys[(g << 6) + (k << 3)];
                float2 y0 = yp[0], y1 = yp[1], y2 = yp[2], y3 = yp[3];
#pragma unroll
                for (int j = 0; j < 4; ++j) {
                    uint4 wq = wpt[(k << 7) + l + (j << 5)];
                    ac2[j] += up2(wq.x) * y0;
                    ac2[j] += up2(wq.y) * y1;
                    ac2[j] += up2(wq.z) * y2;
                    ac2[j] += up2(wq.w) * y3;
                }
            }
        } else {
#pragma unroll
            for (int k = 0; k < 8; ++k) {
                const float2* yp = (const float2*)&ys[(g << 6) + (k << 3)];
                float2 y0 = yp[0], y1 = yp[1], y2 = yp[2], y3 = yp[3];
#pragma unroll
                for (int j = 0; j < 4; ++j) {
                    const float2* wr = (const float2*)(W1d + (((g << 7) + l + (j << 5)) << 6) + (k << 3));
                    ac2[j] += wr[0] * y0;
                    ac2[j] += wr[1] * y1;
                    ac2[j] += wr[2] * y2;
                    ac2[j] += wr[3] * y3;
                }
            }
        }
        float acc[4];
#pragma unroll
        for (int j = 0; j < 4; ++j)
            acc[j] = ac2[j].x + ac2[j].y + b1d[(g << 7) + (j << 5) + l];

        // softmax over v (= lane within 32-lane group), row u = 4g+j
#pragma unroll
        for (int j = 0; j < 4; ++j) {
            float mx = acc[j];
#pragma unroll
            for (int s = 16; s >= 1; s >>= 1) mx = fmaxf(mx, __shfl_xor(mx, s, 32));
            float p = __expf(acc[j] - mx);
            float ssum = p;
#pragma unroll
            for (int s = 16; s >= 1; s >>= 1) ssum += __shfl_xor(ssum, s, 32);
            float pv = __fdividef(p, ssum);
            zs16[((g << 2) + j) * 40 + l] = (u16t)pk_bf16(pv, pv);
        }
    }

    // barrier 2: zs written by all waves must be visible to all waves
    asm volatile("s_waitcnt lgkmcnt(0)" ::: "memory");
    __builtin_amdgcn_s_barrier();
    asm volatile("" ::: "memory");

    // ---------------- phase 4: out = attn . x via MFMA 32x32x16 ----------
    {
        // A frags: attn[u = l31][k = g2*8 + j (+16)]
        bf16x8 A0 = *(const bf16x8*)&zs16[l31 * 40 + g2 * 8];
        bf16x8 A1 = *(const bf16x8*)&zs16[l31 * 40 + 16 + g2 * 8];
        float* __restrict__ obase = out + (size_t)blk * 12288;
#pragma unroll
        for (int i = 0; i < 3; ++i) {
            const int d = wid * 96 + i * 32 + l31;
            const int dq = d >> 2, dl = d & 3;
            float v0[8], v1[8];
#pragma unroll
            for (int j = 0; j < 8; ++j) {
                const int vA = g2 * 8 + j;                 // v rows (vB = vA+16
                const int pq = (dq & ~7) | ((dq ^ vA) & 7);//  has same swizzle)
                v0[j] = xs[vA * 384 + pq * 4 + dl];
                v1[j] = xs[(vA + 16) * 384 + pq * 4 + dl];
            }
            union { uint4 u; bf16x8 v; } B0, B1;
            B0.u.x = pk_bf16(v0[0], v0[1]); B0.u.y = pk_bf16(v0[2], v0[3]);
            B0.u.z = pk_bf16(v0[4], v0[5]); B0.u.w = pk_bf16(v0[6], v0[7]);
            B1.u.x = pk_bf16(v1[0], v1[1]); B1.u.y = pk_bf16(v1[2], v1[3]);
            B1.u.z = pk_bf16(v1[4], v1[5]); B1.u.w = pk_bf16(v1[6], v1[7]);
            f32x16 acc16;
#pragma unroll
            for (int r = 0; r < 16; ++r) acc16[r] = 0.f;
            acc16 = __builtin_amdgcn_mfma_f32_32x32x16_bf16(A0, B0.v, acc16, 0, 0, 0);
            acc16 = __builtin_amdgcn_mfma_f32_32x32x16_bf16(A1, B1.v, acc16, 0, 0, 0);
#pragma unroll
            for (int r = 0; r < 16; ++r) {
                const int u = (r & 3) + 8 * (r >> 2) + 4 * g2;
                obase[u * 384 + d] = acc16[r];
            }
        }
    }
}

// ---------------------------------------------------------------------------
extern "C" void kernel_launch(void* const* d_in, const int* in_sizes, int n_in,
                              void* d_out, int out_size, void* d_ws, size_t ws_size,
                              hipStream_t stream) {
    const float* x   = (const float*)d_in[0];
    const float* W2d = (const float*)d_in[1];
    const float* b2d = (const float*)d_in[2];
    const float* W1d = (const float*)d_in[3];
    const float* b1d = (const float*)d_in[4];
    float* out = (float*)d_out;

    const size_t wt_bytes  = 8 * 8 * 128 * 8 * sizeof(u16t);   // 131072
    const size_t w2b_bytes = 16 * 384 * sizeof(u16t);          // 12288
    if (ws_size >= wt_bytes + w2b_bytes) {
        u16t* Wt = (u16t*)d_ws;
        u16t* W2b = (u16t*)((char*)d_ws + wt_bytes);
        prep_weights<<<35, 256, 0, stream>>>(W1d, W2d, Wt, (uint4*)W2b);
        dynamixer_fused<true><<<4096, 256, 0, stream>>>(x, W2d, b2d, W1d, b1d, Wt, W2b, out);
    } else {
        dynamixer_fused<false><<<4096, 256, 0, stream>>>(x, W2d, b2d, W1d, b1d, nullptr, nullptr, out);
    }
}

// Round 11
// 109.896 us; speedup vs baseline: 1.7312x; 1.0248x over previous
//
#include <hip/hip_runtime.h>
#include <stdint.h>

typedef unsigned short u16t;
typedef __attribute__((ext_vector_type(8))) short bf16x8;
typedef __attribute__((ext_vector_type(4))) float f32x4;
typedef __attribute__((ext_vector_type(16))) float f32x16;

__device__ __forceinline__ float2 up2(uint32_t u) {
    return make_float2(__uint_as_float(u << 16), __uint_as_float(u & 0xFFFF0000u));
}
__device__ __forceinline__ uint32_t pk_bf16(float a, float b) {
    uint32_t r;
    asm("v_cvt_pk_bf16_f32 %0, %1, %2" : "=v"(r) : "v"(a), "v"(b));
    return r;   // lo16 = bf16(a) RNE, hi16 = bf16(b)
}

// pinned 16B global load: compiler cannot sink/serialize asm volatile outputs
#define GLD4(dst, addr, OFF) \
    asm volatile("global_load_dwordx4 %0, %1, off" OFF : "=&v"(dst) : "v"(addr))

// counted vmcnt wait; "memory" stops memory-op reordering, sched_barrier(0)
// stops VALU use-hoisting (rule #18).  vmcnt(N) = count of MY younger loads;
// foreign loads only make the wait more conservative (issue-ordered counter).
#define WAITV(NLIT) do {                                                   \
    asm volatile("s_waitcnt vmcnt(" #NLIT ")" ::: "memory");               \
    __builtin_amdgcn_sched_barrier(0); } while (0)

// issue 8 Wt loads (2 k-groups x 4 o-blocks), offsets k*2048 + j*512
#define WT_ISSUE8(B, A) do {                                               \
    GLD4(B[0], A, "");                GLD4(B[1], A, " offset:512");        \
    GLD4(B[2], A, " offset:1024");    GLD4(B[3], A, " offset:1536");       \
    GLD4(B[4], A, " offset:2048");    GLD4(B[5], A, " offset:2560");       \
    GLD4(B[6], A, " offset:3072");    GLD4(B[7], A, " offset:3584"); } while (0)

#define P3_PROC2(K, BUF) do {                                              \
    _Pragma("unroll")                                                      \
    for (int kk = 0; kk < 2; ++kk) {                                       \
        const float2* yp = (const float2*)&ys[(g << 6) + (((K) + kk) << 3)];\
        float2 y0 = yp[0], y1 = yp[1], y2 = yp[2], y3 = yp[3];             \
        _Pragma("unroll")                                                  \
        for (int j = 0; j < 4; ++j) {                                      \
            uint4 wq = BUF[kk * 4 + j];                                    \
            ac2[j] += up2(wq.x) * y0;                                      \
            ac2[j] += up2(wq.y) * y1;                                      \
            ac2[j] += up2(wq.z) * y2;                                      \
            ac2[j] += up2(wq.w) * y3;                                      \
        }                                                                  \
    } } while (0)

// ---------------------------------------------------------------------------
// Pre-kernel (35 blocks):
//  blocks 0-31 : W1d (1024x64 fp32) -> Wt bf16 [g][k][o][j]   (131072 B)
//  blocks 32-34: W2d (16x384 fp32)  -> W2b bf16 [16][384] row-major (12288 B)
// ---------------------------------------------------------------------------
__global__ void __launch_bounds__(256) prep_weights(const float* __restrict__ W1d,
                                                    const float* __restrict__ W2d,
                                                    u16t* __restrict__ Wt,
                                                    uint4* __restrict__ W2b) {
    int bid = blockIdx.x;
    if (bid < 32) {
        int t = bid * 256 + threadIdx.x;          // 0..8191
        int g = t >> 10, k = (t >> 7) & 7, o = t & 127;
        const float* src = W1d + (((g << 7) + o) << 6) + (k << 3);
        u16t* dst = Wt + ((((g << 3) + k) << 7) + o) * 8;
#pragma unroll
        for (int j = 0; j < 8; ++j) {
            uint32_t u = __float_as_uint(src[j]);
            uint32_t r = (u + 0x7FFFu + ((u >> 16) & 1u)) >> 16;   // RN to bf16
            dst[j] = (u16t)r;
        }
    } else {
        int idx = (bid - 32) * 256 + threadIdx.x;  // 0..767 (chunks of 8 f32)
        const float4* s = (const float4*)W2d + idx * 2;
        float4 A = s[0], B = s[1];
        uint4 p;
        p.x = pk_bf16(A.x, A.y); p.y = pk_bf16(A.z, A.w);
        p.z = pk_bf16(B.x, B.y); p.w = pk_bf16(B.z, B.w);
        W2b[idx] = p;
    }
}

// ---------------------------------------------------------------------------
// Fused kernel: one block (256 thr) per (b,h).  R4 skeleton + asm-forced ILP:
//  phase 1: 12 asm global_load_dwordx4 (pinned, all in flight) -> counted
//           vmcnt -> pk_bf16 -> ds_write_b128;  bf16 tile xs16[32][392]
//  phase 2: y = W2d.x^T via mfma_16x16x32_bf16 (per-wave dup, e-slice write)
//  phase 3: conv1d with DOUBLE-BUFFERED asm Wt batches (8 loads x 4 batches,
//           vmcnt(8) rotation) + softmax -> attn bf16 zs16[32][40]
//  phase 4: out = attn.x via mfma_32x32x16_bf16 (B = 48 ds_read_u16 gathers)
// LDS: 25088 + 2048 + 2560 = 29696 B.  Barriers: 2.  VGPR cap 128 (4 blk/CU).
// ---------------------------------------------------------------------------
template <bool WBF>
__global__ void __launch_bounds__(256, 4) dynamixer_fused(
    const float* __restrict__ x,
    const float* __restrict__ W2d,
    const float* __restrict__ b2d,
    const float* __restrict__ W1d,
    const float* __restrict__ b1d,
    const u16t* __restrict__ Wt,
    const u16t* __restrict__ W2b,
    float* __restrict__ out)
{
    __shared__ u16t xs16[32 * 392];             // bf16 x tile, row stride 392
    __shared__ alignas(16) float ys[512];       // y, flat e*32+w
    __shared__ alignas(16) u16t zs16[32 * 40];  // attn bf16, row stride 40

    const int t = threadIdx.x;
    const int blk = blockIdx.x;                           // b*32 + h
    const float* __restrict__ xsrc = x + (size_t)blk * 12288;
    const int wid = t >> 6, lane = t & 63;
    const int g2 = lane >> 5, l31 = lane & 31;
    const int g = t >> 5, l = t & 31;

    // ---------------- phase 1: asm-pinned stage -> bf16 LDS ----------------
    {
        float4 st[12];
        uint64_t a = (uint64_t)(uintptr_t)xsrc + (uint32_t)(t * 32);
#pragma unroll
        for (int k = 0; k < 6; ++k) {
            GLD4(st[2 * k],     a, "");
            GLD4(st[2 * k + 1], a, " offset:16");
            a += 8192;                       // next pair: p += 256
        }
        // progressive consume: pair k needs my loads 2k,2k+1 -> vmcnt(10-2k)
#pragma unroll
        for (int k = 0; k < 6; ++k) {
            switch (k) {
                case 0: WAITV(10); break;
                case 1: WAITV(8);  break;
                case 2: WAITV(6);  break;
                case 3: WAITV(4);  break;
                case 4: WAITV(2);  break;
                default: WAITV(0); break;
            }
            int p = t + (k << 8);
            int row = p / 48, c = p - row * 48;
            uint4 pk;
            pk.x = pk_bf16(st[2 * k].x,     st[2 * k].y);
            pk.y = pk_bf16(st[2 * k].z,     st[2 * k].w);
            pk.z = pk_bf16(st[2 * k + 1].x, st[2 * k + 1].y);
            pk.w = pk_bf16(st[2 * k + 1].z, st[2 * k + 1].w);
            *(uint4*)&xs16[row * 392 + c * 8] = pk;
        }
    }
    asm volatile("s_waitcnt lgkmcnt(0)" ::: "memory");
    __builtin_amdgcn_s_barrier();
    asm volatile("" ::: "memory");
    __builtin_amdgcn_sched_barrier(0);

    // ---------------- phase 2: conv2d via MFMA 16x16x32 ----------------
    {
        const int g4 = lane >> 4, m = lane & 15;          // A row=e, B col=w=m
        f32x4 c0, c1;
#pragma unroll
        for (int r = 0; r < 4; ++r) { c0[r] = 0.f; c1[r] = 0.f; }
        __builtin_amdgcn_s_setprio(1);
#pragma unroll 4
        for (int ks = 0; ks < 12; ++ks) {
            const int d0 = ks * 32 + g4 * 8;
            bf16x8 a;
            if (WBF) {
                a = *(const bf16x8*)&W2b[m * 384 + d0];
            } else {
                const float* wf = W2d + m * 384 + d0;
                float4 wa = *(const float4*)wf, wb = *(const float4*)(wf + 4);
                union { uint4 u; bf16x8 v; } cvt;
                cvt.u.x = pk_bf16(wa.x, wa.y); cvt.u.y = pk_bf16(wa.z, wa.w);
                cvt.u.z = pk_bf16(wb.x, wb.y); cvt.u.w = pk_bf16(wb.z, wb.w);
                a = cvt.v;
            }
            bf16x8 b0 = *(const bf16x8*)&xs16[m * 392 + d0];
            bf16x8 b1 = *(const bf16x8*)&xs16[(m + 16) * 392 + d0];
            c0 = __builtin_amdgcn_mfma_f32_16x16x32_bf16(a, b0, c0, 0, 0, 0);
            c1 = __builtin_amdgcn_mfma_f32_16x16x32_bf16(a, b1, c1, 0, 0, 0);
        }
        __builtin_amdgcn_s_setprio(0);
        // write only this wave's e-slice [4*wid, 4*wid+4): C row=g4*4+r, col=m
        if (g4 == wid) {
            float4 bb = *(const float4*)&b2d[wid * 4];
            float bbv[4] = {bb.x, bb.y, bb.z, bb.w};
#pragma unroll
            for (int r = 0; r < 4; ++r) {
                ys[(4 * wid + r) * 32 + m]      = c0[r] + bbv[r];
                ys[(4 * wid + r) * 32 + 16 + m] = c1[r] + bbv[r];
            }
        }
    }
    asm volatile("s_waitcnt lgkmcnt(0)" ::: "memory");    // ys visible intra-wave
    __builtin_amdgcn_sched_barrier(0);

    // ---------------- phase 3: conv1d (asm dbuf Wt) + softmax ----------
    {
        float2 ac2[4];
#pragma unroll
        for (int j = 0; j < 4; ++j) ac2[j] = make_float2(0.f, 0.f);
        if (WBF) {
            uint4 bufA[8], bufB[8];
            uint64_t wa = (uint64_t)(uintptr_t)Wt + ((uint32_t)g << 14)
                        + ((uint32_t)l << 4);
            WT_ISSUE8(bufA, wa);  wa += 4096;      // k = 0,1
            WT_ISSUE8(bufB, wa);  wa += 4096;      // k = 2,3
            WAITV(8);                               // bufA ready (8 younger)
            P3_PROC2(0, bufA);
            WT_ISSUE8(bufA, wa);  wa += 4096;      // k = 4,5
            WAITV(8);                               // bufB ready
            P3_PROC2(2, bufB);
            WT_ISSUE8(bufB, wa);                    // k = 6,7
            WAITV(8);                               // bufA (k=4,5) ready
            P3_PROC2(4, bufA);
            WAITV(0);                               // bufB (k=6,7) ready
            P3_PROC2(6, bufB);
        } else {
#pragma unroll
            for (int k = 0; k < 8; ++k) {
                const float2* yp = (const float2*)&ys[(g << 6) + (k << 3)];
                float2 y0 = yp[0], y1 = yp[1], y2 = yp[2], y3 = yp[3];
#pragma unroll
                for (int j = 0; j < 4; ++j) {
                    const float2* wr = (const float2*)(W1d + (((g << 7) + l + (j << 5)) << 6) + (k << 3));
                    ac2[j] += wr[0] * y0;
                    ac2[j] += wr[1] * y1;
                    ac2[j] += wr[2] * y2;
                    ac2[j] += wr[3] * y3;
                }
            }
        }
        float acc[4];
#pragma unroll
        for (int j = 0; j < 4; ++j)
            acc[j] = ac2[j].x + ac2[j].y + b1d[(g << 7) + (j << 5) + l];

        // softmax over v (= lane within 32-lane group), row u = 4g+j
#pragma unroll
        for (int j = 0; j < 4; ++j) {
            float mx = acc[j];
#pragma unroll
            for (int s = 16; s >= 1; s >>= 1) mx = fmaxf(mx, __shfl_xor(mx, s, 32));
            float p = __expf(acc[j] - mx);
            float ssum = p;
#pragma unroll
            for (int s = 16; s >= 1; s >>= 1) ssum += __shfl_xor(ssum, s, 32);
            float pv = __fdividef(p, ssum);
            zs16[((g << 2) + j) * 40 + l] = (u16t)pk_bf16(pv, pv);
        }
    }
    asm volatile("s_waitcnt lgkmcnt(0)" ::: "memory");
    __builtin_amdgcn_s_barrier();
    asm volatile("" ::: "memory");
    __builtin_amdgcn_sched_barrier(0);

    // ---------------- phase 4: out = attn . x via MFMA 32x32x16 ----------
    {
        // A frags: attn[u = l31][k = g2*8 + j (+16)]
        bf16x8 A0 = *(const bf16x8*)&zs16[l31 * 40 + g2 * 8];
        bf16x8 A1 = *(const bf16x8*)&zs16[l31 * 40 + 16 + g2 * 8];
        float* __restrict__ obase = out + (size_t)blk * 12288;
#pragma unroll
        for (int i = 0; i < 3; ++i) {
            const int d = wid * 96 + i * 32 + l31;
            const u16t* __restrict__ xc = xs16 + d;
            bf16x8 B0, B1;
#pragma unroll
            for (int j = 0; j < 8; ++j) {
                B0[j] = (short)xc[(g2 * 8 + j) * 392];
                B1[j] = (short)xc[(16 + g2 * 8 + j) * 392];
            }
            f32x16 acc16;
#pragma unroll
            for (int r = 0; r < 16; ++r) acc16[r] = 0.f;
            __builtin_amdgcn_s_setprio(1);
            acc16 = __builtin_amdgcn_mfma_f32_32x32x16_bf16(A0, B0, acc16, 0, 0, 0);
            acc16 = __builtin_amdgcn_mfma_f32_32x32x16_bf16(A1, B1, acc16, 0, 0, 0);
            __builtin_amdgcn_s_setprio(0);
#pragma unroll
            for (int r = 0; r < 16; ++r) {
                const int u = (r & 3) + 8 * (r >> 2) + 4 * g2;
                obase[u * 384 + d] = acc16[r];
            }
        }
    }
}

// ---------------------------------------------------------------------------
extern "C" void kernel_launch(void* const* d_in, const int* in_sizes, int n_in,
                              void* d_out, int out_size, void* d_ws, size_t ws_size,
                              hipStream_t stream) {
    const float* x   = (const float*)d_in[0];
    const float* W2d = (const float*)d_in[1];
    const float* b2d = (const float*)d_in[2];
    const float* W1d = (const float*)d_in[3];
    const float* b1d = (const float*)d_in[4];
    float* out = (float*)d_out;

    const size_t wt_bytes  = 8 * 8 * 128 * 8 * sizeof(u16t);   // 131072
    const size_t w2b_bytes = 16 * 384 * sizeof(u16t);          // 12288
    if (ws_size >= wt_bytes + w2b_bytes) {
        u16t* Wt = (u16t*)d_ws;
        u16t* W2b = (u16t*)((char*)d_ws + wt_bytes);
        prep_weights<<<35, 256, 0, stream>>>(W1d, W2d, Wt, (uint4*)W2b);
        dynamixer_fused<true><<<4096, 256, 0, stream>>>(x, W2d, b2d, W1d, b1d, Wt, W2b, out);
    } else {
        dynamixer_fused<false><<<4096, 256, 0, stream>>>(x, W2d, b2d, W1d, b1d, nullptr, nullptr, out);
    }
}